// Round 1
// baseline (150.426 us; speedup 1.0000x reference)
//
#include <hip/hip_runtime.h>
#include <hip/hip_bf16.h>
#include <stdint.h>

// Problem constants (fixed by the reference)
#define N_B   16384   // batch
#define D_DIM 1024    // input dim
#define K_K   512     // mixture components
#define L_DIM 128     // latent dim
#define H_DIM 64      // phi hidden

typedef __attribute__((ext_vector_type(8))) short short8;   // 8 bf16 = 4 VGPRs (MFMA A/B frag)
typedef __attribute__((ext_vector_type(4))) float f32x4;    // MFMA C/D frag

__device__ __forceinline__ unsigned short f2bf(float f) {   // fp32 -> bf16 RNE
    union { float f; unsigned int u; } c; c.f = f;
    unsigned int u = c.u;
    unsigned int r = (u + 0x7FFFu + ((u >> 16) & 1u)) >> 16;
    return (unsigned short)r;
}
__device__ __forceinline__ float bf2f(unsigned short h) {
    union { unsigned int u; float f; } c; c.u = ((unsigned int)h) << 16;
    return c.f;
}

// ---------------- kernel 0: W2 (H x D fp32) -> bf16 ----------------
__global__ __launch_bounds__(256) void cvt_w2_kernel(const float* __restrict__ W2,
                                                     unsigned short* __restrict__ W2bf) {
    int i = blockIdx.x * 256 + threadIdx.x;          // float4 index; 64 blocks * 256 = 16384 exactly
    const float4* src = (const float4*)W2;
    float4 v = src[i];
    ushort4 o;
    o.x = f2bf(v.x); o.y = f2bf(v.y); o.z = f2bf(v.z); o.w = f2bf(v.w);
    *(ushort4*)(W2bf + i * 4) = o;
}

// ---------------- kernel 1: h = relu(z@W1+b1) (bf16 out), phi2[k] = ||h@W2+b2||^2 (exact fp32)
// 128 blocks x 128 threads, 4 components per block.
__global__ __launch_bounds__(128) void prep_kernel(
    const float* __restrict__ z, const float* __restrict__ W1,
    const float* __restrict__ b1, const float* __restrict__ W2,
    const float* __restrict__ b2, unsigned short* __restrict__ h_bf,
    float* __restrict__ phi2) {
    __shared__ float zrow[4][L_DIM];
    __shared__ float hsh[4][H_DIM];
    __shared__ float redp[2][4];
    const int tid = threadIdx.x;
    const int kb = blockIdx.x * 4;
#pragma unroll
    for (int kk = 0; kk < 4; ++kk) zrow[kk][tid] = z[(kb + kk) * L_DIM + tid];
    __syncthreads();
    if (tid < H_DIM) {
        float bb = b1[tid];
        float s[4] = {bb, bb, bb, bb};
        for (int l = 0; l < L_DIM; ++l) {
            float w = W1[l * H_DIM + tid];
#pragma unroll
            for (int kk = 0; kk < 4; ++kk) s[kk] += zrow[kk][l] * w;
        }
#pragma unroll
        for (int kk = 0; kk < 4; ++kk) {
            float hv = fmaxf(s[kk], 0.0f);
            hsh[kk][tid] = hv;
            h_bf[(kb + kk) * H_DIM + tid] = f2bf(hv);
        }
    }
    __syncthreads();
    float ss[4] = {0.f, 0.f, 0.f, 0.f};
    for (int d = tid; d < D_DIM; d += 128) {
        float bb = b2[d];
        float a0 = bb, a1 = bb, a2 = bb, a3 = bb;
#pragma unroll
        for (int j = 0; j < H_DIM; ++j) {
            float w = W2[j * D_DIM + d];
            a0 += hsh[0][j] * w; a1 += hsh[1][j] * w;
            a2 += hsh[2][j] * w; a3 += hsh[3][j] * w;
        }
        ss[0] += a0 * a0; ss[1] += a1 * a1; ss[2] += a2 * a2; ss[3] += a3 * a3;
    }
    const int lane = tid & 63, wv = tid >> 6;
#pragma unroll
    for (int kk = 0; kk < 4; ++kk) {
        float v = ss[kk];
#pragma unroll
        for (int o = 1; o < 64; o <<= 1) v += __shfl_xor(v, o, 64);
        if (lane == 0) redp[wv][kk] = v;
    }
    __syncthreads();
    if (tid < 4) phi2[kb + tid] = redp[0][tid] + redp[1][tid];
}

// ---------------- main kernel: per block = one 32-row batch tile ----------------
// stage 1: u = x @ W2^T (waves split D in quarters), also x2[n], xb2[n] = x.b2
// stage 2: S = h @ u^T (512x32, inner 64), fused exp + component-sum epilogue.
__global__ __launch_bounds__(256) void main_kernel(
    const float* __restrict__ x, const unsigned short* __restrict__ W2bf,
    const unsigned short* __restrict__ h_bf, const float* __restrict__ phi2,
    const float* __restrict__ b2, float* __restrict__ lik_sum) {
    __shared__ float upart[4][32][H_DIM];                     // 32 KB fp32 u partials (per wave)
    __shared__ __align__(16) unsigned short u_tile[32 * H_DIM]; // 4 KB bf16 u tile
    __shared__ float phi2s[K_K];                              // 2 KB
    __shared__ __align__(16) float b2l[D_DIM];                // 4 KB
    __shared__ float x2s[32], xb2s[32];
    __shared__ float red[4][32];

    const int tid = threadIdx.x;
    const int wv  = tid >> 6;      // wave 0..3
    const int l   = tid & 63;      // lane
    const int lm  = l & 15;
    const int q   = l >> 4;        // quad 0..3
    const int n0  = blockIdx.x * 32;

    phi2s[tid]       = phi2[tid];
    phi2s[256 + tid] = phi2[256 + tid];
    ((float4*)b2l)[tid] = ((const float4*)b2)[tid];
    if (tid < 32) { x2s[tid] = 0.f; xb2s[tid] = 0.f; }
    __syncthreads();

    // ---- stage 1: this wave's D-quarter ----
    f32x4 c1[2][4] = {};
    float x2p0 = 0.f, x2p1 = 0.f, xbp0 = 0.f, xbp1 = 0.f;
    const int dq = wv * 256;
#pragma unroll
    for (int s = 0; s < 8; ++s) {
        const int dl = dq + s * 32 + q * 8;        // lane's 8-elem chunk along D
        float4 bb0 = *(const float4*)&b2l[dl];
        float4 bb1 = *(const float4*)&b2l[dl + 4];
        short8 af[2];
#pragma unroll
        for (int i = 0; i < 2; ++i) {
            const float* xp = x + (size_t)(n0 + i * 16 + lm) * D_DIM + dl;
            float4 v0 = *(const float4*)xp;
            float4 v1 = *(const float4*)(xp + 4);
            unsigned short u0 = f2bf(v0.x), u1 = f2bf(v0.y), u2 = f2bf(v0.z), u3 = f2bf(v0.w);
            unsigned short u4 = f2bf(v1.x), u5 = f2bf(v1.y), u6 = f2bf(v1.z), u7 = f2bf(v1.w);
            short8 a;
            a[0] = (short)u0; a[1] = (short)u1; a[2] = (short)u2; a[3] = (short)u3;
            a[4] = (short)u4; a[5] = (short)u5; a[6] = (short)u6; a[7] = (short)u7;
            af[i] = a;
            float f0 = bf2f(u0), f1 = bf2f(u1), f2 = bf2f(u2), f3 = bf2f(u3);
            float f4 = bf2f(u4), f5 = bf2f(u5), f6 = bf2f(u6), f7 = bf2f(u7);
            float s2 = f0*f0 + f1*f1 + f2*f2 + f3*f3 + f4*f4 + f5*f5 + f6*f6 + f7*f7;
            float sb = f0*bb0.x + f1*bb0.y + f2*bb0.z + f3*bb0.w
                     + f4*bb1.x + f5*bb1.y + f6*bb1.z + f7*bb1.w;
            if (i == 0) { x2p0 += s2; xbp0 += sb; } else { x2p1 += s2; xbp1 += sb; }
        }
        short8 bfr[4];
#pragma unroll
        for (int j = 0; j < 4; ++j)
            bfr[j] = *(const short8*)(W2bf + (size_t)(j * 16 + lm) * D_DIM + dl);
#pragma unroll
        for (int i = 0; i < 2; ++i)
#pragma unroll
            for (int j = 0; j < 4; ++j)
                c1[i][j] = __builtin_amdgcn_mfma_f32_16x16x32_bf16(af[i], bfr[j], c1[i][j], 0, 0, 0);
    }
    // write u partials (C layout: row = q*4+r, col = lm)
#pragma unroll
    for (int i = 0; i < 2; ++i)
#pragma unroll
        for (int j = 0; j < 4; ++j)
#pragma unroll
            for (int r = 0; r < 4; ++r)
                upart[wv][i * 16 + q * 4 + r][j * 16 + lm] = c1[i][j][r];
    {   // x2/xb2: reduce over the 4 quads of the wave, then atomic across waves (D partials)
        float v0 = x2p0, v1 = x2p1, w0 = xbp0, w1 = xbp1;
        v0 += __shfl_xor(v0, 16, 64); v0 += __shfl_xor(v0, 32, 64);
        v1 += __shfl_xor(v1, 16, 64); v1 += __shfl_xor(v1, 32, 64);
        w0 += __shfl_xor(w0, 16, 64); w0 += __shfl_xor(w0, 32, 64);
        w1 += __shfl_xor(w1, 16, 64); w1 += __shfl_xor(w1, 32, 64);
        if (l < 16) {
            atomicAdd(&x2s[l], v0);       atomicAdd(&x2s[16 + l], v1);
            atomicAdd(&xb2s[l], w0);      atomicAdd(&xb2s[16 + l], w1);
        }
    }
    __syncthreads();
    // sum the 4 D-quarter partials of u, round to bf16
    const float* upf = &upart[0][0][0];
#pragma unroll
    for (int c = 0; c < 8; ++c) {
        int idx = c * 256 + tid;
        float sum = upf[idx] + upf[2048 + idx] + upf[4096 + idx] + upf[6144 + idx];
        u_tile[idx] = f2bf(sum);
    }
    __syncthreads();

    // ---- stage 2: S = h @ u^T, wave wv covers component rows [wv*128, wv*128+128) ----
    f32x4 acc[8][2] = {};
#pragma unroll
    for (int ks = 0; ks < 2; ++ks) {
        const int ko = ks * 32 + q * 8;
        short8 bfr[2];
#pragma unroll
        for (int j = 0; j < 2; ++j)
            bfr[j] = *(const short8*)&u_tile[(j * 16 + lm) * H_DIM + ko];
#pragma unroll
        for (int i = 0; i < 8; ++i) {
            short8 a = *(const short8*)(h_bf + (size_t)(wv * 128 + i * 16 + lm) * H_DIM + ko);
#pragma unroll
            for (int j = 0; j < 2; ++j)
                acc[i][j] = __builtin_amdgcn_mfma_f32_16x16x32_bf16(a, bfr[j], acc[i][j], 0, 0, 0);
        }
    }
    // ---- epilogue: sq = phi2[m] + (x2[n] - 2*xb2[n]) - 2*S; sum_k exp(-sq) ----
    float xn0 = x2s[lm]      - 2.f * xb2s[lm];
    float xn1 = x2s[16 + lm] - 2.f * xb2s[16 + lm];
    float cs0 = 0.f, cs1 = 0.f;
#pragma unroll
    for (int i = 0; i < 8; ++i) {
#pragma unroll
        for (int r = 0; r < 4; ++r) {
            float p2 = phi2s[wv * 128 + i * 16 + q * 4 + r];
            cs0 += __expf(-(p2 + xn0 - 2.f * acc[i][0][r]));
            cs1 += __expf(-(p2 + xn1 - 2.f * acc[i][1][r]));
        }
    }
    cs0 += __shfl_xor(cs0, 16, 64); cs0 += __shfl_xor(cs0, 32, 64);
    cs1 += __shfl_xor(cs1, 16, 64); cs1 += __shfl_xor(cs1, 32, 64);
    if (l < 16) { red[wv][l] = cs0; red[wv][16 + l] = cs1; }
    __syncthreads();
    if (tid < 32)
        lik_sum[n0 + tid] = red[0][tid] + red[1][tid] + red[2][tid] + red[3][tid];
}

// ---------------- kernel 3: out = mean_b log(lik_sum/K + eps) ----------------
__global__ __launch_bounds__(1024) void reduce_kernel(const float* __restrict__ lik,
                                                      float* __restrict__ out) {
    const int tid = threadIdx.x;
    float s = 0.f;
#pragma unroll
    for (int c = 0; c < 16; ++c) {
        int b = c * 1024 + tid;
        s += __logf(lik[b] * (1.0f / (float)K_K) + 1e-9f);
    }
#pragma unroll
    for (int o = 1; o < 64; o <<= 1) s += __shfl_xor(s, o, 64);
    __shared__ float r[16];
    if ((tid & 63) == 0) r[tid >> 6] = s;
    __syncthreads();
    if (tid == 0) {
        float t = 0.f;
#pragma unroll
        for (int i = 0; i < 16; ++i) t += r[i];
        out[0] = t * (1.0f / (float)N_B);
    }
}

extern "C" void kernel_launch(void* const* d_in, const int* in_sizes, int n_in,
                              void* d_out, int out_size, void* d_ws, size_t ws_size,
                              hipStream_t stream) {
    const float* x  = (const float*)d_in[0];
    const float* z  = (const float*)d_in[1];
    const float* W1 = (const float*)d_in[2];
    const float* b1 = (const float*)d_in[3];
    const float* W2 = (const float*)d_in[4];
    const float* b2 = (const float*)d_in[5];

    char* ws = (char*)d_ws;
    unsigned short* W2bf   = (unsigned short*)(ws);            // 128 KB
    unsigned short* h_bf   = (unsigned short*)(ws + 131072);   // 64 KB
    float*          phi2   = (float*)(ws + 196608);            // 2 KB
    float*          liks   = (float*)(ws + 200704);            // 64 KB

    cvt_w2_kernel<<<64, 256, 0, stream>>>(W2, W2bf);
    prep_kernel<<<K_K / 4, 128, 0, stream>>>(z, W1, b1, W2, b2, h_bf, phi2);
    main_kernel<<<N_B / 32, 256, 0, stream>>>(x, W2bf, h_bf, phi2, b2, liks);
    reduce_kernel<<<1, 1024, 0, stream>>>(liks, (float*)d_out);
}

// Round 2
// 148.972 us; speedup vs baseline: 1.0098x; 1.0098x over previous
//
#include <hip/hip_runtime.h>
#include <hip/hip_bf16.h>
#include <stdint.h>

// Problem constants (fixed by the reference)
#define N_B   16384   // batch
#define D_DIM 1024    // input dim
#define K_K   512     // mixture components
#define L_DIM 128     // latent dim
#define H_DIM 64      // phi hidden

typedef __attribute__((ext_vector_type(8))) short short8;   // 8 bf16 = 4 VGPRs (MFMA A/B frag)
typedef __attribute__((ext_vector_type(4))) float f32x4;    // MFMA C/D frag

__device__ __forceinline__ unsigned short f2bf(float f) {   // fp32 -> bf16 RNE (scalar)
    union { float f; unsigned int u; } c; c.f = f;
    unsigned int u = c.u;
    unsigned int r = (u + 0x7FFFu + ((u >> 16) & 1u)) >> 16;
    return (unsigned short)r;
}

__device__ __forceinline__ unsigned int pk2(float a, float b) {  // 2x fp32 -> packed bf16x2
    __hip_bfloat162 t = __float22bfloat162_rn(make_float2(a, b));
    union { __hip_bfloat162 h; unsigned int u; } c; c.h = t;
    return c.u;
}

// ---------------- kernel 1: prep ----------------
// 64 blocks x 256 threads. Per block: 8 components (h = relu(z@W1+b1) -> bf16,
// phi2[k] = ||h@W2+b2||^2 exact fp32), plus 1/64th of W2 -> bf16 conversion.
__global__ __launch_bounds__(256) void prep_kernel(
    const float* __restrict__ z, const float* __restrict__ W1,
    const float* __restrict__ b1, const float* __restrict__ W2,
    const float* __restrict__ b2, unsigned short* __restrict__ W2bf,
    unsigned short* __restrict__ h_bf, float* __restrict__ phi2) {
    __shared__ float zsh[8][L_DIM];     // 4 KB
    __shared__ float hsh[8][H_DIM];     // 2 KB
    __shared__ float redp[4][8];
    const int tid = threadIdx.x;
    const int k0 = blockIdx.x * 8;

    // --- W2 -> bf16: 64 blocks x 256 threads x 1 float4 = 16384 float4 = all of W2
    {
        int i = blockIdx.x * 256 + tid;
        float4 v = ((const float4*)W2)[i];
        uint2 o = make_uint2(pk2(v.x, v.y), pk2(v.z, v.w));
        *(uint2*)(W2bf + i * 4) = o;
    }
    // --- stage z rows for this block's 8 components
#pragma unroll
    for (int c = 0; c < 4; ++c) {
        int idx = c * 256 + tid;
        zsh[idx >> 7][idx & 127] = z[k0 * L_DIM + idx];
    }
    __syncthreads();
    // --- h = relu(z@W1+b1): thread t handles comps (t>>6) and (t>>6)+4 at col t&63
    {
        const int j = tid & 63, kk = tid >> 6;
        float bb = b1[j];
        float s0 = bb, s1 = bb;
        for (int l = 0; l < L_DIM; ++l) {
            float w = W1[l * H_DIM + j];
            s0 += zsh[kk][l] * w;
            s1 += zsh[kk + 4][l] * w;
        }
        float h0 = fmaxf(s0, 0.0f), h1 = fmaxf(s1, 0.0f);
        hsh[kk][j] = h0; hsh[kk + 4][j] = h1;
        h_bf[(k0 + kk) * H_DIM + j]     = f2bf(h0);
        h_bf[(k0 + kk + 4) * H_DIM + j] = f2bf(h1);
    }
    __syncthreads();
    // --- phi2[k] = ||h@W2 + b2||^2, exact fp32
    float ss[8] = {0.f, 0.f, 0.f, 0.f, 0.f, 0.f, 0.f, 0.f};
#pragma unroll
    for (int c = 0; c < 4; ++c) {
        int d = c * 256 + tid;
        float bb = b2[d];
        float a[8];
#pragma unroll
        for (int kk = 0; kk < 8; ++kk) a[kk] = bb;
        for (int j = 0; j < H_DIM; ++j) {
            float w = W2[j * D_DIM + d];
#pragma unroll
            for (int kk = 0; kk < 8; ++kk) a[kk] += hsh[kk][j] * w;
        }
#pragma unroll
        for (int kk = 0; kk < 8; ++kk) ss[kk] += a[kk] * a[kk];
    }
    const int lane = tid & 63, wv = tid >> 6;
#pragma unroll
    for (int kk = 0; kk < 8; ++kk) {
        float v = ss[kk];
#pragma unroll
        for (int o = 1; o < 64; o <<= 1) v += __shfl_xor(v, o, 64);
        if (lane == 0) redp[wv][kk] = v;
    }
    __syncthreads();
    if (tid < 8) phi2[k0 + tid] = redp[0][tid] + redp[1][tid] + redp[2][tid] + redp[3][tid];
}

// ---------------- main kernel: per block = one 32-row batch tile ----------------
// stage 1: u = x @ W2^T (waves split D in quarters), x2[n], xb2[n] = x.b2
// stage 2: S = h @ u^T (512x32, inner 64), fused exp + component-sum + log + mean
__global__ __launch_bounds__(256) void main_kernel(
    const float* __restrict__ x, const unsigned short* __restrict__ W2bf,
    const unsigned short* __restrict__ h_bf, const float* __restrict__ phi2,
    const float* __restrict__ b2, float* __restrict__ out) {
    __shared__ float upart[4][32][68];                          // 34 KB, padded (+4) rows
    __shared__ __align__(16) unsigned short u_tile[32 * 72];    // 4.5 KB, stride 72
    __shared__ float phi2s[K_K];                                // 2 KB
    __shared__ __align__(16) float b2l[D_DIM];                  // 4 KB
    __shared__ float x2s[32], xb2s[32];
    __shared__ float red[4][32];

    const int tid = threadIdx.x;
    const int wv  = tid >> 6;      // wave 0..3
    const int l   = tid & 63;      // lane
    const int lm  = l & 15;
    const int q   = l >> 4;        // quad 0..3
    const int n0  = blockIdx.x * 32;

    phi2s[tid]       = phi2[tid];
    phi2s[256 + tid] = phi2[256 + tid];
    ((float4*)b2l)[tid] = ((const float4*)b2)[tid];
    if (tid < 32) { x2s[tid] = 0.f; xb2s[tid] = 0.f; }
    __syncthreads();

    // ---- stage 1: this wave's D-quarter ----
    f32x4 c1[2][4] = {};
    float x2p0 = 0.f, x2p1 = 0.f, xbp0 = 0.f, xbp1 = 0.f;
    const int dq = wv * 256;
#pragma unroll
    for (int s = 0; s < 8; ++s) {
        const int dl = dq + s * 32 + q * 8;        // lane's 8-elem chunk along D
        float4 bb0 = *(const float4*)&b2l[dl];
        float4 bb1 = *(const float4*)&b2l[dl + 4];
        short8 af[2];
#pragma unroll
        for (int i = 0; i < 2; ++i) {
            const float* xp = x + (size_t)(n0 + i * 16 + lm) * D_DIM + dl;
            float4 v0 = *(const float4*)xp;
            float4 v1 = *(const float4*)(xp + 4);
            float s2 = v0.x*v0.x + v0.y*v0.y + v0.z*v0.z + v0.w*v0.w
                     + v1.x*v1.x + v1.y*v1.y + v1.z*v1.z + v1.w*v1.w;
            float sb = v0.x*bb0.x + v0.y*bb0.y + v0.z*bb0.z + v0.w*bb0.w
                     + v1.x*bb1.x + v1.y*bb1.y + v1.z*bb1.z + v1.w*bb1.w;
            union { short8 s8; unsigned int u[4]; } packu;
            packu.u[0] = pk2(v0.x, v0.y);
            packu.u[1] = pk2(v0.z, v0.w);
            packu.u[2] = pk2(v1.x, v1.y);
            packu.u[3] = pk2(v1.z, v1.w);
            af[i] = packu.s8;
            if (i == 0) { x2p0 += s2; xbp0 += sb; } else { x2p1 += s2; xbp1 += sb; }
        }
        short8 bfr[4];
#pragma unroll
        for (int j = 0; j < 4; ++j)
            bfr[j] = *(const short8*)(W2bf + (size_t)(j * 16 + lm) * D_DIM + dl);
#pragma unroll
        for (int i = 0; i < 2; ++i)
#pragma unroll
            for (int j = 0; j < 4; ++j)
                c1[i][j] = __builtin_amdgcn_mfma_f32_16x16x32_bf16(af[i], bfr[j], c1[i][j], 0, 0, 0);
    }
    // write u partials (C layout: row = q*4+r, col = lm); padded rows -> 2-way (free)
#pragma unroll
    for (int i = 0; i < 2; ++i)
#pragma unroll
        for (int j = 0; j < 4; ++j)
#pragma unroll
            for (int r = 0; r < 4; ++r)
                upart[wv][i * 16 + q * 4 + r][j * 16 + lm] = c1[i][j][r];
    {   // x2/xb2: reduce over the 4 quads of the wave, then atomic across waves (D partials)
        float v0 = x2p0, v1 = x2p1, w0 = xbp0, w1 = xbp1;
        v0 += __shfl_xor(v0, 16, 64); v0 += __shfl_xor(v0, 32, 64);
        v1 += __shfl_xor(v1, 16, 64); v1 += __shfl_xor(v1, 32, 64);
        w0 += __shfl_xor(w0, 16, 64); w0 += __shfl_xor(w0, 32, 64);
        w1 += __shfl_xor(w1, 16, 64); w1 += __shfl_xor(w1, 32, 64);
        if (l < 16) {
            atomicAdd(&x2s[l], v0);       atomicAdd(&x2s[16 + l], v1);
            atomicAdd(&xb2s[l], w0);      atomicAdd(&xb2s[16 + l], w1);
        }
    }
    __syncthreads();
    // sum the 4 D-quarter partials of u, round to bf16 (u_tile row stride 72)
#pragma unroll
    for (int c = 0; c < 8; ++c) {
        int idx = c * 256 + tid;
        int row = idx >> 6, col = idx & 63;
        float sum = upart[0][row][col] + upart[1][row][col]
                  + upart[2][row][col] + upart[3][row][col];
        u_tile[row * 72 + col] = f2bf(sum);
    }
    __syncthreads();

    // ---- stage 2: S = h @ u^T, wave wv covers component rows [wv*128, wv*128+128) ----
    f32x4 acc[8][2] = {};
#pragma unroll
    for (int ks = 0; ks < 2; ++ks) {
        const int ko = ks * 32 + q * 8;
        short8 bfr[2];
#pragma unroll
        for (int j = 0; j < 2; ++j)
            bfr[j] = *(const short8*)&u_tile[(j * 16 + lm) * 72 + ko];
#pragma unroll
        for (int i = 0; i < 8; ++i) {
            short8 a = *(const short8*)(h_bf + (size_t)(wv * 128 + i * 16 + lm) * H_DIM + ko);
#pragma unroll
            for (int j = 0; j < 2; ++j)
                acc[i][j] = __builtin_amdgcn_mfma_f32_16x16x32_bf16(a, bfr[j], acc[i][j], 0, 0, 0);
        }
    }
    // ---- epilogue: sq = phi2[m] + (x2[n] - 2*xb2[n]) - 2*S; sum_k exp(-sq) ----
    float xn0 = x2s[lm]      - 2.f * xb2s[lm];
    float xn1 = x2s[16 + lm] - 2.f * xb2s[16 + lm];
    float cs0 = 0.f, cs1 = 0.f;
#pragma unroll
    for (int i = 0; i < 8; ++i) {
#pragma unroll
        for (int r = 0; r < 4; ++r) {
            float p2 = phi2s[wv * 128 + i * 16 + q * 4 + r];
            cs0 += __expf(-(p2 + xn0 - 2.f * acc[i][0][r]));
            cs1 += __expf(-(p2 + xn1 - 2.f * acc[i][1][r]));
        }
    }
    cs0 += __shfl_xor(cs0, 16, 64); cs0 += __shfl_xor(cs0, 32, 64);
    cs1 += __shfl_xor(cs1, 16, 64); cs1 += __shfl_xor(cs1, 32, 64);
    if (l < 16) { red[wv][l] = cs0; red[wv][16 + l] = cs1; }
    __syncthreads();
    // ---- fused final reduction: mean over this block's 32 rows of log(mean_k lik + eps)
    if (tid < 32) {
        float row_lik = red[0][tid] + red[1][tid] + red[2][tid] + red[3][tid];
        float lg = __logf(row_lik * (1.0f / (float)K_K) + 1e-9f);
        lg += __shfl_xor(lg, 1, 64);
        lg += __shfl_xor(lg, 2, 64);
        lg += __shfl_xor(lg, 4, 64);
        lg += __shfl_xor(lg, 8, 64);
        lg += __shfl_xor(lg, 16, 64);
        if (tid == 0) atomicAdd(out, lg * (1.0f / (float)N_B));
    }
}

extern "C" void kernel_launch(void* const* d_in, const int* in_sizes, int n_in,
                              void* d_out, int out_size, void* d_ws, size_t ws_size,
                              hipStream_t stream) {
    const float* x  = (const float*)d_in[0];
    const float* z  = (const float*)d_in[1];
    const float* W1 = (const float*)d_in[2];
    const float* b1 = (const float*)d_in[3];
    const float* W2 = (const float*)d_in[4];
    const float* b2 = (const float*)d_in[5];

    char* ws = (char*)d_ws;
    unsigned short* W2bf = (unsigned short*)(ws);            // 128 KB
    unsigned short* h_bf = (unsigned short*)(ws + 131072);   // 64 KB
    float*          phi2 = (float*)(ws + 196608);            // 2 KB

    hipMemsetAsync(d_out, 0, sizeof(float), stream);
    prep_kernel<<<64, 256, 0, stream>>>(z, W1, b1, W2, b2, W2bf, h_bf, phi2);
    main_kernel<<<N_B / 32, 256, 0, stream>>>(x, W2bf, h_bf, phi2, b2, (float*)d_out);
}